// Round 5
// baseline (41.308 us; speedup 1.0000x reference)
//
#include <hip/hip_runtime.h>

// LowFreqPenaltyLoss: mean(|truncated 2-D DCT (8x8) of each 256x256 image|)
// delta: [256,3,256,256] f32 -> scalar f32.
// Basis C[k,n] = 2*cos(pi*(2n+1)*k/512), identical for H and W.
// Per image: u[w][i] = sum_h C[i,h]*X[h,w]; low[i,j] = sum_w C[j,w]*u[w][i].
//
// R5: 3072 blocks (quarter-image = 64 rows each; 12 blocks/CU -> finer
// load-balance granularity than R4's 1536), manual 4-row load batching
// (16 independent dword loads in flight per thread), pre-abs partials to
// ws, pair+abs+sum reduce kernel. Dword stride-64 loads (beat float4 in R1).

#define INV_COUNT (1.0f / 49152.0f)  // 256*3*8*8

__global__ __launch_bounds__(256, 3) void lowfreq_main(
    const float* __restrict__ delta, float* __restrict__ ws,
    float* __restrict__ out)
{
    __shared__ float c_row[256][8];  // basis, wave-uniform broadcast by row h
    __shared__ float c_col[8][256];  // transposed, per-lane epilogue reads
    __shared__ float pacc[4][64];

    const int t = threadIdx.x;
    const int wave = t >> 6;
    const int lane = t & 63;
    const int bid = blockIdx.x;
    const int img = bid >> 2;        // (n,c) image index
    const int q = bid & 3;           // quarter: rows [64q, 64q+64)

    // Phase 0: DCT-II basis row t via Chebyshev recurrence:
    // cos((k+1)a) = 2cos(a)cos(ka) - cos((k-1)a); store 2*cos(ka).
    {
        const float a = 3.14159265358979323846f * (2.0f * (float)t + 1.0f)
                        * (1.0f / 512.0f);
        const float ca = cosf(a);
        float ckm1 = 1.0f;   // cos(0)
        float ck   = ca;     // cos(a)
        c_row[t][0] = 2.0f;       c_col[0][t] = 2.0f;
        c_row[t][1] = 2.0f * ca;  c_col[1][t] = 2.0f * ca;
        #pragma unroll
        for (int k = 2; k < 8; ++k) {
            const float cn = 2.0f * ca * ck - ckm1;
            ckm1 = ck; ck = cn;
            c_row[t][k] = 2.0f * cn;
            c_col[k][t] = 2.0f * cn;
        }
    }
    __syncthreads();

    // Phase 1: this block streams rows [64q, 64q+64); wave owns 16 of them.
    // Thread owns columns {lane, lane+64, lane+128, lane+192} (dword loads,
    // stride 64). Manual 4-row batches: 16 independent loads, then 128 FMAs.
    const int row0 = (q << 6) + (wave << 4);
    const float* gp = delta + (size_t)img * 65536 + (size_t)row0 * 256 + lane;

    float u[4][8];
    #pragma unroll
    for (int c = 0; c < 4; ++c)
        #pragma unroll
        for (int i = 0; i < 8; ++i) u[c][i] = 0.0f;

    #pragma unroll
    for (int rb = 0; rb < 4; ++rb) {
        float x[4][4];
        #pragma unroll
        for (int rr = 0; rr < 4; ++rr) {
            const float* p = gp + (size_t)((rb << 2) + rr) * 256;
            x[rr][0] = p[0];
            x[rr][1] = p[64];
            x[rr][2] = p[128];
            x[rr][3] = p[192];
        }
        #pragma unroll
        for (int rr = 0; rr < 4; ++rr) {
            const int h = row0 + (rb << 2) + rr;
            const float4 cA = *reinterpret_cast<const float4*>(&c_row[h][0]);
            const float4 cB = *reinterpret_cast<const float4*>(&c_row[h][4]);
            const float cc[8] = {cA.x, cA.y, cA.z, cA.w, cB.x, cB.y, cB.z, cB.w};
            #pragma unroll
            for (int i = 0; i < 8; ++i) {
                u[0][i] = fmaf(cc[i], x[rr][0], u[0][i]);
                u[1][i] = fmaf(cc[i], x[rr][1], u[1][i]);
                u[2][i] = fmaf(cc[i], x[rr][2], u[2][i]);
                u[3][i] = fmaf(cc[i], x[rr][3], u[3][i]);
            }
        }
    }

    // Phase 2: per-thread partial low[i][j] over its 4 columns (w = c*64+lane).
    float cw[4][8];
    #pragma unroll
    for (int c = 0; c < 4; ++c)
        #pragma unroll
        for (int j = 0; j < 8; ++j)
            cw[c][j] = c_col[j][(c << 6) + lane];

    float v[64];
    #pragma unroll
    for (int i = 0; i < 8; ++i)
        #pragma unroll
        for (int j = 0; j < 8; ++j) {
            float s = u[0][i] * cw[0][j];
            s = fmaf(u[1][i], cw[1][j], s);
            s = fmaf(u[2][i], cw[2][j], s);
            s = fmaf(u[3][i], cw[3][j], s);
            v[(i << 3) + j] = s;
        }

    // Phase 3: slot-splitting butterfly — transpose+reduce 64 slots across the
    // wave; at the end lane l holds the wave total of slot l = (i<<3|j).
    #pragma unroll
    for (int s = 0; s < 6; ++s) {
        const int m = 1 << s;
        const bool bit = (lane & m) != 0;
        #pragma unroll
        for (int k = 0; k < (64 >> (s + 1)); ++k) {
            const float a = v[2 * k];
            const float b = v[2 * k + 1];
            const float keep = bit ? b : a;
            const float send = bit ? a : b;
            const float recv = __shfl_xor(send, m, 64);
            v[k] = keep + recv;
        }
    }

    pacc[wave][lane] = v[0];
    __syncthreads();

    // Phase 4: combine 4 waves; write PRE-ABS quarter-image partials to ws.
    if (t < 64) {
        const float s4 = pacc[0][t] + pacc[1][t] + pacc[2][t] + pacc[3][t];
        ws[(size_t)bid * 64 + t] = s4;
        if (bid == 0 && t == 0) out[0] = 0.0f;  // stream-ordered before reduce
    }
}

// Sum the four quarter-image partials, abs, sum all 49152 slots into out.
__global__ __launch_bounds__(256) void lowfreq_reduce(
    const float* __restrict__ ws, float* __restrict__ out)
{
    __shared__ float acc[4];
    const int t = threadIdx.x;
    const int wave = t >> 6;
    const int lane = t & 63;
    const int g = blockIdx.x * 256 + t;       // 192*256 = 49152 = 768*64
    const int img = g >> 6;
    const int slot = g & 63;

    const float s = ws[(size_t)(4 * img + 0) * 64 + slot]
                  + ws[(size_t)(4 * img + 1) * 64 + slot]
                  + ws[(size_t)(4 * img + 2) * 64 + slot]
                  + ws[(size_t)(4 * img + 3) * 64 + slot];
    float a = fabsf(s);
    #pragma unroll
    for (int m = 1; m < 64; m <<= 1) a += __shfl_xor(a, m, 64);
    if (lane == 0) acc[wave] = a;
    __syncthreads();
    if (t == 0)
        atomicAdd(out, (acc[0] + acc[1] + acc[2] + acc[3]) * INV_COUNT);
}

extern "C" void kernel_launch(void* const* d_in, const int* in_sizes, int n_in,
                              void* d_out, int out_size, void* d_ws, size_t ws_size,
                              hipStream_t stream)
{
    const float* delta = (const float*)d_in[0];
    float* out = (float*)d_out;
    float* ws = (float*)d_ws;  // 3072*64*4 B = 786 KB
    lowfreq_main<<<3072, 256, 0, stream>>>(delta, ws, out);
    lowfreq_reduce<<<192, 256, 0, stream>>>(ws, out);
}